// Round 15
// baseline (439.704 us; speedup 1.0000x reference)
//
#include <hip/hip_runtime.h>

#define NYTOT 16384
#define NXP 4096
#define MTOT 65536   // B * NY
#define CYC 128
#define CXC 256
#define DIMC 384

typedef __attribute__((ext_vector_type(8))) _Float16 half8;
typedef __attribute__((ext_vector_type(4))) _Float16 half4;
typedef __attribute__((ext_vector_type(4))) float floatx4;
typedef __attribute__((ext_vector_type(2))) float floatx2;

using half_t = _Float16;

struct alignas(16) HF8 { half_t h[8]; };

__device__ __forceinline__ float fmed3(float a, float b, float c) {
  return __builtin_amdgcn_fmed3f(a, b, c);
}

// ---------------- K0: merged prep — xq table + fp16 weights + st zero ----
__global__ __launch_bounds__(256) void prep_kernel(
    const float* __restrict__ x_points, float4* __restrict__ xq,
    const float* __restrict__ W1, const float* __restrict__ W2,
    const float* __restrict__ W3, half_t* __restrict__ wout,
    float* __restrict__ st) {
#pragma clang fp contract(off)
  const int bid = blockIdx.x;
  if (bid == 416) {
    int t = threadIdx.x;
    for (int k = t; k < 1792; k += 256) st[k] = 0.f;
    return;
  }
  if (bid < 64) {
    int j = bid * 256 + threadIdx.x;          // 0..16383
    int b = j >> 12, jj = j & 4095;
    const float* p = x_points + (size_t)b * NXP * 3 + 3 * jj;
    float x0 = p[0], x1 = p[1], x2 = p[2];
    float sx = (x0 * x0 + x1 * x1) + x2 * x2; // ref order
    float4 v; v.x = x0; v.y = x1; v.z = x2; v.w = sx;
    xq[j] = v;
  } else {
    int i = (bid - 64) * 256 + threadIdx.x;   // float4 index, 0..90111
    const float* src; half_t* dst; int j;
    if (i < 49152)      { src = W1; dst = wout;          j = i; }
    else if (i < 81920) { src = W2; dst = wout + 196608; j = i - 49152; }
    else                { src = W3; dst = wout + 327680; j = i - 81920; }
    floatx4 v = ((const floatx4*)src)[j];
    half4 h;
#pragma unroll
    for (int e = 0; e < 4; ++e) h[e] = (half_t)v[e];
    ((half4*)dst)[j] = h;
  }
}

// ---------------- K1: 3-NN interpolation (round-5/8/10/14 verified) ------
__global__ __launch_bounds__(1024, 8) void interp_kernel(
    const float* __restrict__ y_points, const float* __restrict__ y_feats,
    const float* __restrict__ x_feats, const float4* __restrict__ xq,
    half_t* __restrict__ A0) {
#pragma clang fp contract(off)
  __shared__ float pd[16][128][3];        // 24 KB partial dists
  __shared__ int   pi[16][128][3];        // 24 KB partial idx
  __shared__ float t2s[128];
  __shared__ float sw[3][128];
  __shared__ int   si[3][128];
  const int b = blockIdx.x >> 7;
  const int chunk = blockIdx.x & 127;
  const int t = threadIdx.x;
  const int lane = t & 63;
  const int seg = t >> 6;                 // wave id == segment, 0..15
  const int yloc = lane << 1;             // my 2 y's: yloc, yloc+1

  const float* yp = y_points + ((size_t)b * NYTOT + chunk * 128 + yloc) * 3;
  floatx2 Y0 = {yp[0], yp[3]};
  floatx2 Y1 = {yp[1], yp[4]};
  floatx2 Y2 = {yp[2], yp[5]};
  floatx2 SY = (Y0 * Y0 + Y1 * Y1) + Y2 * Y2;       // ref order per element

  const float4* xqs = xq + (size_t)b * NXP;
  const int jb = __builtin_amdgcn_readfirstlane(seg * 256);

  // ---- phase 1: value-only top-3 per (seg, y) via med3/min ----
  floatx2 D0 = {1e30f, 1e30f}, D1 = D0, D2 = D0;
#pragma unroll 8
  for (int jj = 0; jj < 256; ++jj) {
    float4 p = xqs[jb + jj];                        // wave-uniform load
    floatx2 inner = (Y0 * p.x + Y1 * p.y) + Y2 * p.z;
    floatx2 d = (SY + p.w) - 2.0f * inner;
    D2.x = fmed3(d.x, D1.x, D2.x);  D2.y = fmed3(d.y, D1.y, D2.y);
    D1.x = fmed3(d.x, D0.x, D1.x);  D1.y = fmed3(d.y, D0.y, D1.y);
    D0.x = fminf(d.x, D0.x);        D0.y = fminf(d.y, D0.y);
  }
  pd[seg][yloc][0] = D0.x; pd[seg][yloc][1] = D1.x; pd[seg][yloc][2] = D2.x;
  pd[seg][yloc + 1][0] = D0.y; pd[seg][yloc + 1][1] = D1.y; pd[seg][yloc + 1][2] = D2.y;
  __syncthreads();

  // global 3rd-smallest per y
  if (t < 128) {
    float m0 = 1e30f, m1 = 1e30f, m2 = 1e30f;
#pragma unroll
    for (int s = 0; s < 16; ++s)
#pragma unroll
      for (int c = 0; c < 3; ++c) {
        float v = pd[s][t][c];
        m2 = fmed3(v, m1, m2);
        m1 = fmed3(v, m0, m1);
        m0 = fminf(v, m0);
      }
    t2s[t] = m2;
  }
  __syncthreads();

  // ---- phase 2: gated stable index recovery ----
  const float t2a = t2s[yloc], t2b = t2s[yloc + 1];
  const float tmax = fmaxf(t2a, t2b);
  float e0a = 1e30f, e1a = 1e30f, e2a = 1e30f; int k0a = 0, k1a = 0, k2a = 0;
  float e0b = 1e30f, e1b = 1e30f, e2b = 1e30f; int k0b = 0, k1b = 0, k2b = 0;
#pragma unroll 4
  for (int jj = 0; jj < 256; ++jj) {
    float4 p = xqs[jb + jj];
    floatx2 inner = (Y0 * p.x + Y1 * p.y) + Y2 * p.z;
    floatx2 d = (SY + p.w) - 2.0f * inner;
    if (fminf(d.x, d.y) <= tmax) {                  // rare
      int j = jb + jj;
      {
        float dv = d.x;
        bool l0 = dv < e0a, l1 = dv < e1a, l2 = dv < e2a;
        e2a = l1 ? e1a : (l2 ? dv : e2a);  k2a = l1 ? k1a : (l2 ? j : k2a);
        e1a = l0 ? e0a : (l1 ? dv : e1a);  k1a = l0 ? k0a : (l1 ? j : k1a);
        e0a = l0 ? dv : e0a;               k0a = l0 ? j : k0a;
      }
      {
        float dv = d.y;
        bool l0 = dv < e0b, l1 = dv < e1b, l2 = dv < e2b;
        e2b = l1 ? e1b : (l2 ? dv : e2b);  k2b = l1 ? k1b : (l2 ? j : k2b);
        e1b = l0 ? e0b : (l1 ? dv : e1b);  k1b = l0 ? k0b : (l1 ? j : k1b);
        e0b = l0 ? dv : e0b;               k0b = l0 ? j : k0b;
      }
    }
  }
  pd[seg][yloc][0] = e0a; pd[seg][yloc][1] = e1a; pd[seg][yloc][2] = e2a;
  pi[seg][yloc][0] = k0a; pi[seg][yloc][1] = k1a; pi[seg][yloc][2] = k2a;
  pd[seg][yloc + 1][0] = e0b; pd[seg][yloc + 1][1] = e1b; pd[seg][yloc + 1][2] = e2b;
  pi[seg][yloc + 1][0] = k0b; pi[seg][yloc + 1][1] = k1b; pi[seg][yloc + 1][2] = k2b;
  __syncthreads();

  // 48-way stable merge (seg-ascending) + weights
  if (t < 128) {
    float f0 = 1e30f, f1 = 1e30f, f2 = 1e30f;
    int m0i = 0, m1i = 0, m2i = 0;
#pragma unroll
    for (int s = 0; s < 16; ++s)
#pragma unroll
      for (int c = 0; c < 3; ++c) {
        float d = pd[s][t][c]; int j = pi[s][t][c];
        bool l0 = d < f0, l1 = d < f1, l2 = d < f2;
        f2 = l1 ? f1 : (l2 ? d : f2);  m2i = l1 ? m1i : (l2 ? j : m2i);
        f1 = l0 ? f0 : (l1 ? d : f1);  m1i = l0 ? m0i : (l1 ? j : m1i);
        f0 = l0 ? d : f0;              m0i = l0 ? j : m0i;
      }
    float w0 = 1.0f / (f0 + 1e-8f), w1 = 1.0f / (f1 + 1e-8f), w2 = 1.0f / (f2 + 1e-8f);
    float ws = (w0 + w1) + w2;
    sw[0][t] = w0 / ws; sw[1][t] = w1 / ws; sw[2][t] = w2 / ws;
    si[0][t] = m0i; si[1][t] = m1i; si[2][t] = m2i;
  }
  __syncthreads();

  // ---- gather ----
  const floatx4* xf4 = (const floatx4*)(x_feats + (size_t)b * NXP * CXC);
  const floatx4* yf4 = (const floatx4*)(y_feats + ((size_t)b * NYTOT + chunk * 128) * CYC);
  half_t* fb = A0 + ((size_t)b * NYTOT + chunk * 128) * DIMC;
  {
    const int q = t & 63;
    const int ysub = t >> 6;
    for (int y2 = ysub; y2 < 128; y2 += 16) {
      int j0 = si[0][y2], j1 = si[1][y2], j2 = si[2][y2];
      float a0 = sw[0][y2], a1 = sw[1][y2], a2 = sw[2][y2];
      floatx4 v0 = xf4[(size_t)j0 * 64 + q];
      floatx4 v1 = xf4[(size_t)j1 * 64 + q];
      floatx4 v2 = xf4[(size_t)j2 * 64 + q];
      half4 h;
#pragma unroll
      for (int e = 0; e < 4; ++e)
        h[e] = (half_t)fmaf(v2[e], a2, fmaf(v1[e], a1, v0[e] * a0));
      *(half4*)&fb[(size_t)y2 * DIMC + CYC + q * 4] = h;
    }
  }
  {
    const int q2 = t & 31;
    const int ysub2 = t >> 5;
    for (int y2 = ysub2; y2 < 128; y2 += 32) {
      floatx4 v = yf4[(size_t)y2 * 32 + q2];
      half4 h;
#pragma unroll
      for (int e = 0; e < 4; ++e) h[e] = (half_t)v[e];
      *(half4*)&fb[(size_t)y2 * DIMC + q2 * 4] = h;
    }
  }
}

// ---------------- GEMM 256x128, 2-phase pipelined + T5 setprio ----------
// Only change vs r14: s_setprio(1)/(0) around the MFMA cluster. The
// 2-phase schedule has wave role-diversity (staging vs compute), so the
// CU scheduler can prefer MFMA-issuing waves (T5, m218b/m224 regime).
template<int K, int O, int NTN, bool BN>
__global__ __launch_bounds__(512) void gemm256p(
    const half_t* __restrict__ A, const half_t* __restrict__ Wh,
    const float* __restrict__ bias, half_t* __restrict__ C,
    float* __restrict__ sums, const float* __restrict__ ssA) {
  __shared__ __align__(16) short As[16][2][512];     // 32 KB (single buf)
  __shared__ __align__(16) short Bs[2][8][2][512];   // 32 KB (double buf)
  __shared__ float stats[4][2][128];                 // 4 KB
  constexpr int NWG = (MTOT / 256) * NTN;            // multiple of 8
  constexpr int NT = K / 64;
  const int lin = (blockIdx.x & 7) * (NWG >> 3) + (blockIdx.x >> 3);
  const int m0 = (lin / NTN) * 256;
  const int n0 = (lin % NTN) * 128;
  const int tid = threadIdx.x;
  const int lane = tid & 63;
  const int wid = tid >> 6;            // 0..7
  const int wm = wid >> 1, wn = wid & 1;
  const int lm = lane & 15;
  const int lk = (lane >> 4) * 8;
  const int r = tid & 255;             // A-stage row
  const int hh = tid >> 8;             // A-stage k-half (wave-uniform)
  floatx4 acc[4][4] = {};
  half8 in[4];

  // prologue: B(0) -> Bs[0]; A(0) -> regs
#pragma unroll
  for (int c = 0; c < 2; ++c) {
    int id = wid * 2 + c;              // 0..15 (wave-uniform)
    int sub = id >> 1, ks = id & 1;
    const half_t* src = Wh + (size_t)(n0 + sub * 16 + lm) * K + (ks * 32 + lk);
    __builtin_amdgcn_global_load_lds(
        (const __attribute__((address_space(1))) void*)src,
        (__attribute__((address_space(3))) void*)&Bs[0][sub][ks][0], 16, 0, 0);
  }
  {
    const half_t* arow = A + (size_t)(m0 + r) * K + hh * 32;
#pragma unroll
    for (int g = 0; g < 4; ++g) in[g] = *(const half8*)&arow[g * 8];
  }
  int cur = 0;

  for (int t = 0; t < NT; ++t) {
    const int k0 = t * 64;
    __syncthreads();                   // (A) As free; prev-iter vmem drained
#pragma unroll
    for (int g = 0; g < 4; ++g) {
      half8 h;
      if constexpr (BN) {
        int kcu = __builtin_amdgcn_readfirstlane(k0 + hh * 32 + g * 8);
#pragma unroll
        for (int e = 0; e < 8; ++e) {
          float f = fmaxf((float)in[g][e] * ssA[kcu + e] + ssA[K + kcu + e], 0.f);
          h[e] = (half_t)f;
        }
      } else {
        h = in[g];
      }
      *(half8*)&As[r >> 4][hh][(g * 16 + (r & 15)) * 8] = h;
    }
    __syncthreads();                   // (B) As + Bs[cur] ready
    if (t + 1 < NT) {
      const int k1 = k0 + 64;
#pragma unroll
      for (int c = 0; c < 2; ++c) {    // B(t+1) -> Bs[cur^1]
        int id = wid * 2 + c;
        int sub = id >> 1, ks = id & 1;
        const half_t* src = Wh + (size_t)(n0 + sub * 16 + lm) * K + (k1 + ks * 32 + lk);
        __builtin_amdgcn_global_load_lds(
            (const __attribute__((address_space(1))) void*)src,
            (__attribute__((address_space(3))) void*)&Bs[cur ^ 1][sub][ks][0], 16, 0, 0);
      }
      const half_t* arow = A + (size_t)(m0 + r) * K + k1 + hh * 32;
#pragma unroll
      for (int g = 0; g < 4; ++g) in[g] = *(const half8*)&arow[g * 8];
    }
    // compute tile t (latency of the new loads hides under this)
    __builtin_amdgcn_s_setprio(1);
#pragma unroll
    for (int ks = 0; ks < 2; ++ks) {
      half8 af[4], bfm[4];
#pragma unroll
      for (int i = 0; i < 4; ++i) af[i] = *(const half8*)&As[wm * 4 + i][ks][lane * 8];
#pragma unroll
      for (int j = 0; j < 4; ++j) bfm[j] = *(const half8*)&Bs[cur][wn * 4 + j][ks][lane * 8];
#pragma unroll
      for (int i = 0; i < 4; ++i)
#pragma unroll
        for (int j = 0; j < 4; ++j)
          acc[i][j] = __builtin_amdgcn_mfma_f32_16x16x32_f16(af[i], bfm[j], acc[i][j], 0, 0, 0);
    }
    __builtin_amdgcn_s_setprio(0);
    cur ^= 1;
  }

  // epilogue: C/D layout col=lane&15, row=(lane>>4)*4+rr
  float ps[4], pq[4];
#pragma unroll
  for (int j = 0; j < 4; ++j) {
    int nn = n0 + wn * 64 + j * 16 + lm;
    float bv = bias[nn];
    float psum = 0.f, psq = 0.f;
#pragma unroll
    for (int i = 0; i < 4; ++i) {
      int mr = m0 + wm * 64 + i * 16 + (lane >> 4) * 4;
#pragma unroll
      for (int rr = 0; rr < 4; ++rr) {
        float z = acc[i][j][rr] + bv;
        C[(size_t)(mr + rr) * O + nn] = (half_t)z;
        psum += z; psq += z * z;
      }
    }
    psum += __shfl_xor(psum, 16, 64); psq += __shfl_xor(psq, 16, 64);
    psum += __shfl_xor(psum, 32, 64); psq += __shfl_xor(psq, 32, 64);
    ps[j] = psum; pq[j] = psq;
  }
  __syncthreads();                     // all MFMA/LDS reads done
  if ((lane >> 4) == 0) {
#pragma unroll
    for (int j = 0; j < 4; ++j) {
      int ch = wn * 64 + j * 16 + lm;  // 0..127, disjoint per (wn,j)
      stats[wm][0][ch] = ps[j];
      stats[wm][1][ch] = pq[j];
    }
  }
  __syncthreads();
  if (tid < 256) {
    int s = tid >> 7, ch = tid & 127;
    float v = ((stats[0][s][ch] + stats[1][s][ch]) + stats[2][s][ch]) + stats[3][s][ch];
    atomicAdd(&sums[(s ? O : 0) + n0 + ch], v);
  }
}

// ---------------- GEMM 128x128, 2-phase pipelined + T5 (gemm3, TOUT) -----
template<int K, int O, bool BN, bool TOUT>
__global__ __launch_bounds__(256) void gemm128p(
    const half_t* __restrict__ A, const half_t* __restrict__ Wh,
    const float* __restrict__ bias, half_t* __restrict__ C,
    float* __restrict__ sums, const float* __restrict__ ssA) {
  __shared__ __align__(16) short As[8][2][512];      // 16 KB
  __shared__ __align__(16) short Bs[2][8][2][512];   // 32 KB
  __shared__ float stats[2][2][128];                 // 2 KB
  constexpr int NT = K / 64;
  const int m0 = blockIdx.x * 128;
  const int n0 = blockIdx.y * 128;
  const int tid = threadIdx.x;
  const int lane = tid & 63;
  const int wid = tid >> 6;
  const int wm = wid >> 1, wn = wid & 1;
  const int lm = lane & 15;
  const int lk = (lane >> 4) * 8;
  const int r = tid & 127;
  const int hh = tid >> 7;             // wave-uniform
  floatx4 acc[4][4] = {};
  half8 in[4];

#pragma unroll
  for (int c = 0; c < 4; ++c) {
    int id = wid * 4 + c;              // 0..15
    int sub = id >> 1, ks = id & 1;
    const half_t* src = Wh + (size_t)(n0 + sub * 16 + lm) * K + (ks * 32 + lk);
    __builtin_amdgcn_global_load_lds(
        (const __attribute__((address_space(1))) void*)src,
        (__attribute__((address_space(3))) void*)&Bs[0][sub][ks][0], 16, 0, 0);
  }
  {
    const half_t* arow = A + (size_t)(m0 + r) * K + hh * 32;
#pragma unroll
    for (int g = 0; g < 4; ++g) in[g] = *(const half8*)&arow[g * 8];
  }
  int cur = 0;

  for (int t = 0; t < NT; ++t) {
    const int k0 = t * 64;
    __syncthreads();                   // (A)
#pragma unroll
    for (int g = 0; g < 4; ++g) {
      half8 h;
      if constexpr (BN) {
        int kcu = __builtin_amdgcn_readfirstlane(k0 + hh * 32 + g * 8);
#pragma unroll
        for (int e = 0; e < 8; ++e) {
          float f = fmaxf((float)in[g][e] * ssA[kcu + e] + ssA[K + kcu + e], 0.f);
          h[e] = (half_t)f;
        }
      } else {
        h = in[g];
      }
      *(half8*)&As[r >> 4][hh][(g * 16 + (r & 15)) * 8] = h;
    }
    __syncthreads();                   // (B)
    if (t + 1 < NT) {
      const int k1 = k0 + 64;
#pragma unroll
      for (int c = 0; c < 4; ++c) {
        int id = wid * 4 + c;
        int sub = id >> 1, ks = id & 1;
        const half_t* src = Wh + (size_t)(n0 + sub * 16 + lm) * K + (k1 + ks * 32 + lk);
        __builtin_amdgcn_global_load_lds(
            (const __attribute__((address_space(1))) void*)src,
            (__attribute__((address_space(3))) void*)&Bs[cur ^ 1][sub][ks][0], 16, 0, 0);
      }
      const half_t* arow = A + (size_t)(m0 + r) * K + k1 + hh * 32;
#pragma unroll
      for (int g = 0; g < 4; ++g) in[g] = *(const half8*)&arow[g * 8];
    }
    __builtin_amdgcn_s_setprio(1);
#pragma unroll
    for (int ks = 0; ks < 2; ++ks) {
      half8 af[4], bfm[4];
#pragma unroll
      for (int i = 0; i < 4; ++i) af[i] = *(const half8*)&As[wm * 4 + i][ks][lane * 8];
#pragma unroll
      for (int j = 0; j < 4; ++j) bfm[j] = *(const half8*)&Bs[cur][wn * 4 + j][ks][lane * 8];
#pragma unroll
      for (int i = 0; i < 4; ++i)
#pragma unroll
        for (int j = 0; j < 4; ++j)
          acc[i][j] = __builtin_amdgcn_mfma_f32_16x16x32_f16(af[i], bfm[j], acc[i][j], 0, 0, 0);
    }
    __builtin_amdgcn_s_setprio(0);
    cur ^= 1;
  }

  const int bb = m0 >> 14;             // block-uniform batch (TOUT)
  const int nbase = (m0 & (NYTOT - 1)) + wm * 64 + (lane >> 4) * 4;
  float ps[4], pq[4];
#pragma unroll
  for (int j = 0; j < 4; ++j) {
    int nn = n0 + wn * 64 + j * 16 + lm;
    float bv = bias[nn];
    float psum = 0.f, psq = 0.f;
#pragma unroll
    for (int i = 0; i < 4; ++i) {
      half4 hv;
#pragma unroll
      for (int rr = 0; rr < 4; ++rr) {
        float z = acc[i][j][rr] + bv;
        hv[rr] = (half_t)z;
        psum += z; psq += z * z;
      }
      if constexpr (TOUT) {
        *(half4*)&C[((size_t)(bb * O + nn)) * NYTOT + nbase + i * 16] = hv;
      } else {
        int mr = m0 + wm * 64 + i * 16 + (lane >> 4) * 4;
#pragma unroll
        for (int rr = 0; rr < 4; ++rr)
          C[(size_t)(mr + rr) * O + nn] = hv[rr];
      }
    }
    psum += __shfl_xor(psum, 16, 64); psq += __shfl_xor(psq, 16, 64);
    psum += __shfl_xor(psum, 32, 64); psq += __shfl_xor(psq, 32, 64);
    ps[j] = psum; pq[j] = psq;
  }
  __syncthreads();
  if ((lane >> 4) == 0) {
#pragma unroll
    for (int j = 0; j < 4; ++j) {
      int ch = wn * 64 + j * 16 + lm;
      stats[wm][0][ch] = ps[j];
      stats[wm][1][ch] = pq[j];
    }
  }
  __syncthreads();
  if (tid < 256) {
    int s = tid >> 7, ch = tid & 127;
    float v = stats[0][s][ch] + stats[1][s][ch];
    atomicAdd(&sums[(s ? O : 0) + n0 + ch], v);
  }
}

// ---------------- finalize BN scale/shift ----------
__global__ void finalize_kernel(const float* __restrict__ sums, const float* __restrict__ g,
                                const float* __restrict__ be, float* __restrict__ ss, int O) {
  int c = threadIdx.x;
  if (c < O) {
    const float invN = 1.0f / 65536.0f;
    float mean = sums[c] * invN;
    float var = sums[O + c] * invN - mean * mean;
    float sc = g[c] / sqrtf(var + 1e-5f);
    float sh = be[c] - mean * sc;
    if (!isfinite(sc) || !isfinite(sh)) { sc = 1.0f; sh = 0.0f; }
    ss[c] = sc;
    ss[O + c] = sh;
  }
}

// ---------------- final: elementwise BN3+ReLU fp16->fp32 ----------------
__global__ __launch_bounds__(256) void bnfin_kernel(
    const half_t* __restrict__ Z, const float* __restrict__ ss,
    float* __restrict__ out) {
  size_t i = (size_t)blockIdx.x * 256 + threadIdx.x;   // HF8 index
  int c = (int)((i * 8) >> 14) & 127;
  float sc = ss[c], sh = ss[128 + c];
  HF8 v = ((const HF8*)Z)[i];
  floatx4 o0, o1;
#pragma unroll
  for (int e = 0; e < 4; ++e) {
    o0[e] = fmaxf((float)v.h[e] * sc + sh, 0.f);
    o1[e] = fmaxf((float)v.h[4 + e] * sc + sh, 0.f);
  }
  ((floatx4*)out)[i * 2] = o0;
  ((floatx4*)out)[i * 2 + 1] = o1;
}

extern "C" void kernel_launch(void* const* d_in, const int* in_sizes, int n_in,
                              void* d_out, int out_size, void* d_ws, size_t ws_size,
                              hipStream_t stream) {
  const float* y_points = (const float*)d_in[0];
  const float* y_feats  = (const float*)d_in[1];
  const float* x_points = (const float*)d_in[2];
  const float* x_feats  = (const float*)d_in[3];
  const float* W1 = (const float*)d_in[4];  const float* b1 = (const float*)d_in[5];
  const float* g1 = (const float*)d_in[6];  const float* be1 = (const float*)d_in[7];
  const float* W2 = (const float*)d_in[8];  const float* b2 = (const float*)d_in[9];
  const float* g2 = (const float*)d_in[10]; const float* be2 = (const float*)d_in[11];
  const float* W3 = (const float*)d_in[12]; const float* b3 = (const float*)d_in[13];
  const float* g3 = (const float*)d_in[14]; const float* be3 = (const float*)d_in[15];

  // workspace layout (identical bounds — no new bytes):
  //   [0, 50.33MB)        : A0 fp16 [M,384]  (later aliased by z2)
  //   [50.33MB, 117.44MB) : z1 fp16 [M,512]  (xq pre-gemm1; z3T after gemm2)
  //   [117.44MB, ...)     : BN stats (st[0..3583])
  // d_out (33.5 MB) doubles as scratch for fp16 weights until bnfin.
  char* ws = (char*)d_ws;
  half_t* A0 = (half_t*)ws;                      // 65536*384*2 = 50,331,648
  half_t* z1 = (half_t*)(ws + 50331648);         // 65536*512*2 = 67,108,864
  half_t* z2 = (half_t*)ws;                      // alias A0 (dead after gemm1)
  half_t* z3T = (half_t*)(ws + 50331648);        // alias z1 (dead after gemm2)
  float4* xq = (float4*)(ws + 50331648);         // alias z1 head (dead pre-gemm1)
  float* st = (float*)(ws + 117440512);
  // st floats: sum1/sq1 @0 (1024), sum2/sq2 @1024 (512), sum3/sq3 @1536 (256),
  //            ss1 @1792 (1024), ss2 @2816 (512), ss3 @3328 (256)
  half_t* W1h = (half_t*)d_out;                  // 512*384  = 196608 halfs
  half_t* W2h = W1h + 196608;                    // 256*512  = 131072 halfs
  half_t* W3h = W1h + 327680;                    // 128*256  =  32768 halfs

  prep_kernel<<<417, 256, 0, stream>>>(x_points, xq, W1, W2, W3, W1h, st);
  interp_kernel<<<512, 1024, 0, stream>>>(y_points, y_feats, x_feats, xq, A0);

  // gemm1: 256x128 tile, 1024 blocks (XCD-swizzled, n-fastest), pipelined
  gemm256p<384, 512, 4, false><<<1024, 512, 0, stream>>>(A0, W1h, b1, z1, st + 0, nullptr);
  finalize_kernel<<<1, 512, 0, stream>>>(st + 0, g1, be1, st + 1792, 512);

  // gemm2: BN1+ReLU fused into A-staging, pipelined
  gemm256p<512, 256, 2, true><<<512, 512, 0, stream>>>(z1, W2h, b2, z2, st + 1024, st + 1792);
  finalize_kernel<<<1, 256, 0, stream>>>(st + 1024, g2, be2, st + 2816, 256);

  // gemm3: BN2+ReLU fused, pipelined, TOUT layout
  gemm128p<256, 128, true, true><<<dim3(512, 1), 256, 0, stream>>>(z2, W3h, b3, z3T, st + 1536, st + 2816);
  finalize_kernel<<<1, 128, 0, stream>>>(st + 1536, g3, be3, st + 3328, 128);

  // final: elementwise BN3+ReLU fp16->fp32 (no transpose needed)
  bnfin_kernel<<<4096, 256, 0, stream>>>(z3T, st + 3328, (float*)d_out);
}